// Round 1
// baseline (333.504 us; speedup 1.0000x reference)
//
#include <hip/hip_runtime.h>
#include <math.h>

#define N_NODES 10000
#define N_EDGES 160000
#define IN_FEATS 512
#define HEADS 8
#define OUT_FEATS 64
#define HF (HEADS * OUT_FEATS)   // 512
#define NEG_SLOPE 0.2f

// ---------------- zero scratch ints (counts + cursor) ----------------
__global__ void zero_ints(int* p, int n) {
    int i = blockIdx.x * blockDim.x + threadIdx.x;
    if (i < n) p[i] = 0;
}

// ---------------- fp32 GEMM: C[M,512] = A[M,512] * B[512,512] ----------------
#define TILE 64
#define BK 16
__global__ __launch_bounds__(256) void gemm_h(const float* __restrict__ A,
                                              const float* __restrict__ B,
                                              float* __restrict__ C, int M) {
    __shared__ float As[BK][TILE];   // As[k][m]  (A staged transposed)
    __shared__ float Bs[BK][TILE];   // Bs[k][n]
    const int tid = threadIdx.x;
    const int row0 = blockIdx.x * TILE;
    const int col0 = blockIdx.y * TILE;
    const int tx = tid % 16, ty = tid / 16;       // 16x16 threads, 4x4 micro-tile
    const int arow = tid % 64, akq = tid / 64;    // A load: row, k-quad
    const int bkr  = tid / 16, bnq = tid % 16;    // B load: k-row, n-quad

    float acc[4][4] = {};

    for (int k0 = 0; k0 < IN_FEATS; k0 += BK) {
        float4 av = make_float4(0.f, 0.f, 0.f, 0.f);
        const int grow = row0 + arow;
        if (grow < M)
            av = *reinterpret_cast<const float4*>(A + (size_t)grow * IN_FEATS + k0 + akq * 4);
        float4 bv = *reinterpret_cast<const float4*>(B + (size_t)(k0 + bkr) * HF + col0 + bnq * 4);

        __syncthreads();   // previous iteration's LDS reads done
        As[akq * 4 + 0][arow] = av.x;
        As[akq * 4 + 1][arow] = av.y;
        As[akq * 4 + 2][arow] = av.z;
        As[akq * 4 + 3][arow] = av.w;
        *reinterpret_cast<float4*>(&Bs[bkr][bnq * 4]) = bv;
        __syncthreads();

        #pragma unroll
        for (int kk = 0; kk < BK; ++kk) {
            float4 a4 = *reinterpret_cast<const float4*>(&As[kk][ty * 4]);
            float4 b4 = *reinterpret_cast<const float4*>(&Bs[kk][tx * 4]);
            float a[4] = {a4.x, a4.y, a4.z, a4.w};
            float b[4] = {b4.x, b4.y, b4.z, b4.w};
            #pragma unroll
            for (int i = 0; i < 4; ++i)
                #pragma unroll
                for (int j = 0; j < 4; ++j)
                    acc[i][j] = fmaf(a[i], b[j], acc[i][j]);
        }
    }

    const int crow0 = row0 + ty * 4;
    const int ccol  = col0 + tx * 4;
    #pragma unroll
    for (int i = 0; i < 4; ++i) {
        if (crow0 + i < M) {
            float4 o = make_float4(acc[i][0], acc[i][1], acc[i][2], acc[i][3]);
            *reinterpret_cast<float4*>(C + (size_t)(crow0 + i) * HF + ccol) = o;
        }
    }
}

// ---------------- el/er: one wave per (node, head) ----------------
__global__ __launch_bounds__(256) void eler_kernel(const float* __restrict__ h,
                                                   const float* __restrict__ al,
                                                   const float* __restrict__ ar,
                                                   float* __restrict__ el,
                                                   float* __restrict__ er) {
    const int gw   = (blockIdx.x * blockDim.x + threadIdx.x) >> 6;  // n*HEADS + hh
    const int lane = threadIdx.x & 63;
    if (gw >= N_NODES * HEADS) return;
    const int n  = gw >> 3;
    const int hh = gw & 7;
    const float v = h[(size_t)n * HF + hh * OUT_FEATS + lane];
    float l = v * al[hh * OUT_FEATS + lane];
    float r = v * ar[hh * OUT_FEATS + lane];
    #pragma unroll
    for (int off = 32; off; off >>= 1) {
        l += __shfl_xor(l, off);
        r += __shfl_xor(r, off);
    }
    if (lane == 0) { el[gw] = l; er[gw] = r; }
}

// ---------------- CSR build ----------------
__global__ void hist_kernel(const int* __restrict__ dst, int* __restrict__ counts) {
    int e = blockIdx.x * blockDim.x + threadIdx.x;
    if (e < N_EDGES) atomicAdd(&counts[dst[e]], 1);
}

__global__ __launch_bounds__(1024) void scan_kernel(const int* __restrict__ counts,
                                                    int* __restrict__ row_ptr) {
    __shared__ int buf[1024];
    const int t = threadIdx.x;
    int carry = 0;
    for (int base = 0; base < N_NODES; base += 1024) {
        const int idx = base + t;
        int v = (idx < N_NODES) ? counts[idx] : 0;
        int x = v;
        buf[t] = x;
        __syncthreads();
        for (int off = 1; off < 1024; off <<= 1) {
            int y = (t >= off) ? buf[t - off] : 0;
            __syncthreads();
            x += y;
            buf[t] = x;
            __syncthreads();
        }
        if (idx < N_NODES) row_ptr[idx] = carry + x - v;   // exclusive
        carry += buf[1023];
        __syncthreads();
    }
    if (t == 0) row_ptr[N_NODES] = carry;
}

__global__ void scatter_kernel(const int* __restrict__ src, const int* __restrict__ dst,
                               const int* __restrict__ row_ptr, int* __restrict__ cursor,
                               int* __restrict__ ssrc) {
    int e = blockIdx.x * blockDim.x + threadIdx.x;
    if (e >= N_EDGES) return;
    int d = dst[e];
    int pos = row_ptr[d] + atomicAdd(&cursor[d], 1);
    ssrc[pos] = src[e];
}

// ---------------- softmax + aggregation: one wave per (node, head) ----------------
__global__ __launch_bounds__(256) void aggregate_kernel(const float* __restrict__ h,
                                                        const float* __restrict__ el,
                                                        const float* __restrict__ er,
                                                        const float* __restrict__ bias,
                                                        const int* __restrict__ row_ptr,
                                                        const int* __restrict__ ssrc,
                                                        float* __restrict__ out) {
    const int gw   = (blockIdx.x * blockDim.x + threadIdx.x) >> 6;  // n*HEADS + hh
    const int lane = threadIdx.x & 63;
    if (gw >= N_NODES * HEADS) return;
    const int n  = gw >> 3;
    const int hh = gw & 7;
    const int beg = row_ptr[n];
    const int deg = row_ptr[n + 1] - beg;
    const float bv = bias[hh * OUT_FEATS + lane];
    const size_t obase = (size_t)n * HF + hh * OUT_FEATS + lane;
    if (deg == 0) { out[obase] = bv; return; }

    const float ernh = er[gw];

    // pass 1a: max logit over incoming edges
    float m = -INFINITY;
    for (int i = lane; i < deg; i += 64) {
        float e = el[ssrc[beg + i] * HEADS + hh] + ernh;
        e = e > 0.f ? e : NEG_SLOPE * e;
        m = fmaxf(m, e);
    }
    #pragma unroll
    for (int off = 32; off; off >>= 1) m = fmaxf(m, __shfl_xor(m, off));

    // pass 1b: sum of exp
    float ssum = 0.f;
    for (int i = lane; i < deg; i += 64) {
        float e = el[ssrc[beg + i] * HEADS + hh] + ernh;
        e = e > 0.f ? e : NEG_SLOPE * e;
        ssum += __expf(e - m);
    }
    #pragma unroll
    for (int off = 32; off; off >>= 1) ssum += __shfl_xor(ssum, off);
    const float inv = 1.0f / ssum;

    // pass 2: lanes = features, loop edges
    float acc = 0.f;
    for (int k = 0; k < deg; ++k) {
        const int s = ssrc[beg + k];
        float e = el[s * HEADS + hh] + ernh;
        e = e > 0.f ? e : NEG_SLOPE * e;
        const float a = __expf(e - m) * inv;
        acc = fmaf(a, h[(size_t)s * HF + hh * OUT_FEATS + lane], acc);
    }
    out[obase] = acc + bv;
}

// ---------------- launch ----------------
extern "C" void kernel_launch(void* const* d_in, const int* in_sizes, int n_in,
                              void* d_out, int out_size, void* d_ws, size_t ws_size,
                              hipStream_t stream) {
    const float* feat   = (const float*)d_in[0];
    const float* W      = (const float*)d_in[1];
    const float* attn_l = (const float*)d_in[2];
    const float* attn_r = (const float*)d_in[3];
    const float* bias   = (const float*)d_in[4];
    const int*   src    = (const int*)d_in[5];
    const int*   dst    = (const int*)d_in[6];
    float* out = (float*)d_out;

    // workspace layout (all 4-byte elements)
    char* ws = (char*)d_ws;
    float* h_buf   = (float*)ws;                         ws += (size_t)N_NODES * HF * 4;
    float* el_buf  = (float*)ws;                         ws += (size_t)N_NODES * HEADS * 4;
    float* er_buf  = (float*)ws;                         ws += (size_t)N_NODES * HEADS * 4;
    int*   row_ptr = (int*)ws;                           ws += (size_t)(N_NODES + 1) * 4;
    int*   counts  = (int*)ws;                           ws += (size_t)N_NODES * 4;
    int*   cursor  = (int*)ws;                           ws += (size_t)N_NODES * 4;
    int*   ssrc    = (int*)ws;                           ws += (size_t)N_EDGES * 4;

    // 1) zero counts + cursor (contiguous, 2*N ints)
    zero_ints<<<(2 * N_NODES + 255) / 256, 256, 0, stream>>>(counts, 2 * N_NODES);

    // 2) projection GEMM
    dim3 ggrid((N_NODES + TILE - 1) / TILE, HF / TILE);
    gemm_h<<<ggrid, 256, 0, stream>>>(feat, W, h_buf, N_NODES);

    // 3) per-node attention logits
    int nwaves = N_NODES * HEADS;
    eler_kernel<<<(nwaves * 64 + 255) / 256, 256, 0, stream>>>(h_buf, attn_l, attn_r, el_buf, er_buf);

    // 4) CSR by dst
    hist_kernel<<<(N_EDGES + 255) / 256, 256, 0, stream>>>(dst, counts);
    scan_kernel<<<1, 1024, 0, stream>>>(counts, row_ptr);
    scatter_kernel<<<(N_EDGES + 255) / 256, 256, 0, stream>>>(src, dst, row_ptr, cursor, ssrc);

    // 5) edge-softmax + weighted aggregation (+bias)
    aggregate_kernel<<<(nwaves * 64 + 255) / 256, 256, 0, stream>>>(
        h_buf, el_buf, er_buf, bias, row_ptr, ssrc, out);
}

// Round 2
// 220.054 us; speedup vs baseline: 1.5156x; 1.5156x over previous
//
#include <hip/hip_runtime.h>
#include <math.h>

#define N_NODES 10000
#define N_EDGES 160000
#define IN_FEATS 512
#define HEADS 8
#define OUT_FEATS 64
#define HF (HEADS * OUT_FEATS)   // 512
#define NEG_SLOPE 0.2f

typedef float  f32x4  __attribute__((ext_vector_type(4)));
typedef __bf16 bf16x8 __attribute__((ext_vector_type(8)));
typedef short  s16x8  __attribute__((ext_vector_type(8)));

__device__ __forceinline__ void split_bf16(float x, unsigned short& h, unsigned short& l) {
    unsigned u = __float_as_uint(x);
    h = (unsigned short)(u >> 16);
    float hf = __uint_as_float(u & 0xFFFF0000u);
    l = (unsigned short)(__float_as_uint(x - hf) >> 16);
}

// ---------------- zero scratch ints (counts + cursor) ----------------
__global__ void zero_ints(int* p, int n) {
    int i = blockIdx.x * blockDim.x + threadIdx.x;
    if (i < n) p[i] = 0;
}

// ---------------- W transpose + bf16 hi/lo split: Wt[n][k] ----------------
#define TW 64
__global__ __launch_bounds__(256) void prep_w(const float* __restrict__ W,
                                              unsigned short* __restrict__ Bt_hi,
                                              unsigned short* __restrict__ Bt_lo) {
    __shared__ float tile[TW][TW + 1];
    const int tid = threadIdx.x;
    const int k0 = blockIdx.x * TW;
    const int n0 = blockIdx.y * TW;
    #pragma unroll
    for (int i = 0; i < 4; ++i) {
        int f = tid + 256 * i;
        int r = f >> 4, c4 = f & 15;           // r: k offset, c4: n chunk
        float4 v = *reinterpret_cast<const float4*>(W + (size_t)(k0 + r) * HF + n0 + c4 * 4);
        tile[r][c4 * 4 + 0] = v.x;
        tile[r][c4 * 4 + 1] = v.y;
        tile[r][c4 * 4 + 2] = v.z;
        tile[r][c4 * 4 + 3] = v.w;
    }
    __syncthreads();
    #pragma unroll
    for (int i = 0; i < 4; ++i) {
        int f = tid + 256 * i;
        int rn = f >> 4, c4 = f & 15;          // rn: n offset, c4: k chunk
        ushort4 hi, lo;
        split_bf16(tile[c4 * 4 + 0][rn], hi.x, lo.x);
        split_bf16(tile[c4 * 4 + 1][rn], hi.y, lo.y);
        split_bf16(tile[c4 * 4 + 2][rn], hi.z, lo.z);
        split_bf16(tile[c4 * 4 + 3][rn], hi.w, lo.w);
        size_t off = (size_t)(n0 + rn) * IN_FEATS + k0 + c4 * 4;
        *reinterpret_cast<ushort4*>(Bt_hi + off) = hi;
        *reinterpret_cast<ushort4*>(Bt_lo + off) = lo;
    }
}

// ---------------- split-bf16 MFMA GEMM: C[M,512] = A * B, fp32-accurate ----
#define GTM 128
#define GTN 128
#define GBK 32
__global__ __launch_bounds__(256) void gemm_mfma(const float* __restrict__ A,
                                                 const unsigned short* __restrict__ Bt_hi,
                                                 const unsigned short* __restrict__ Bt_lo,
                                                 float* __restrict__ C, int M) {
    __shared__ unsigned short sAhi[GTM][GBK];
    __shared__ unsigned short sAlo[GTM][GBK];
    __shared__ unsigned short sBhi[GTN][GBK];
    __shared__ unsigned short sBlo[GTN][GBK];

    const int tid  = threadIdx.x;
    const int lane = tid & 63;
    const int w    = tid >> 6;
    const int wm   = w >> 1, wn = w & 1;
    const int m16  = lane & 15, quad = lane >> 4;
    const int row0 = blockIdx.x * GTM;
    const int col0 = blockIdx.y * GTN;
    const int lr   = tid >> 3;   // 0..31
    const int lc4  = tid & 7;    // 4-element column chunk

    f32x4 acc[4][4] = {};

    for (int k0 = 0; k0 < IN_FEATS; k0 += GBK) {
        float4  av[4];
        ushort4 bh[4], bl[4];
        #pragma unroll
        for (int i = 0; i < 4; ++i) {
            int r = lr + 32 * i;
            int grow = row0 + r;
            av[i] = (grow < M)
                ? *reinterpret_cast<const float4*>(A + (size_t)grow * IN_FEATS + k0 + lc4 * 4)
                : make_float4(0.f, 0.f, 0.f, 0.f);
            size_t boff = (size_t)(col0 + r) * IN_FEATS + k0 + lc4 * 4;
            bh[i] = *reinterpret_cast<const ushort4*>(Bt_hi + boff);
            bl[i] = *reinterpret_cast<const ushort4*>(Bt_lo + boff);
        }
        __syncthreads();
        #pragma unroll
        for (int i = 0; i < 4; ++i) {
            int r = lr + 32 * i;
            ushort4 ah, al;
            split_bf16(av[i].x, ah.x, al.x);
            split_bf16(av[i].y, ah.y, al.y);
            split_bf16(av[i].z, ah.z, al.z);
            split_bf16(av[i].w, ah.w, al.w);
            *reinterpret_cast<ushort4*>(&sAhi[r][lc4 * 4]) = ah;
            *reinterpret_cast<ushort4*>(&sAlo[r][lc4 * 4]) = al;
            *reinterpret_cast<ushort4*>(&sBhi[r][lc4 * 4]) = bh[i];
            *reinterpret_cast<ushort4*>(&sBlo[r][lc4 * 4]) = bl[i];
        }
        __syncthreads();

        s16x8 fah[4], fal[4], fbh[4], fbl[4];
        #pragma unroll
        for (int mi = 0; mi < 4; ++mi) {
            int rm = wm * 64 + mi * 16 + m16;
            fah[mi] = *reinterpret_cast<const s16x8*>(&sAhi[rm][quad * 8]);
            fal[mi] = *reinterpret_cast<const s16x8*>(&sAlo[rm][quad * 8]);
        }
        #pragma unroll
        for (int ni = 0; ni < 4; ++ni) {
            int rn = wn * 64 + ni * 16 + m16;
            fbh[ni] = *reinterpret_cast<const s16x8*>(&sBhi[rn][quad * 8]);
            fbl[ni] = *reinterpret_cast<const s16x8*>(&sBlo[rn][quad * 8]);
        }
        #pragma unroll
        for (int mi = 0; mi < 4; ++mi) {
            #pragma unroll
            for (int ni = 0; ni < 4; ++ni) {
                acc[mi][ni] = __builtin_amdgcn_mfma_f32_16x16x32_bf16(
                    __builtin_bit_cast(bf16x8, fah[mi]), __builtin_bit_cast(bf16x8, fbh[ni]),
                    acc[mi][ni], 0, 0, 0);
                acc[mi][ni] = __builtin_amdgcn_mfma_f32_16x16x32_bf16(
                    __builtin_bit_cast(bf16x8, fah[mi]), __builtin_bit_cast(bf16x8, fbl[ni]),
                    acc[mi][ni], 0, 0, 0);
                acc[mi][ni] = __builtin_amdgcn_mfma_f32_16x16x32_bf16(
                    __builtin_bit_cast(bf16x8, fal[mi]), __builtin_bit_cast(bf16x8, fbh[ni]),
                    acc[mi][ni], 0, 0, 0);
            }
        }
    }

    // epilogue: row = quad*4 + reg, col = lane&15 (verified C/D layout)
    #pragma unroll
    for (int mi = 0; mi < 4; ++mi) {
        #pragma unroll
        for (int r = 0; r < 4; ++r) {
            int grow = row0 + wm * 64 + mi * 16 + quad * 4 + r;
            if (grow < M) {
                #pragma unroll
                for (int ni = 0; ni < 4; ++ni)
                    C[(size_t)grow * HF + col0 + wn * 64 + ni * 16 + m16] = acc[mi][ni][r];
            }
        }
    }
}

// ---------------- el/er: one wave per (node, head) ----------------
__global__ __launch_bounds__(256) void eler_kernel(const float* __restrict__ h,
                                                   const float* __restrict__ al,
                                                   const float* __restrict__ ar,
                                                   float* __restrict__ el,
                                                   float* __restrict__ er) {
    const int gw   = (blockIdx.x * blockDim.x + threadIdx.x) >> 6;
    const int lane = threadIdx.x & 63;
    if (gw >= N_NODES * HEADS) return;
    const int n  = gw >> 3;
    const int hh = gw & 7;
    const float v = h[(size_t)n * HF + hh * OUT_FEATS + lane];
    float l = v * al[hh * OUT_FEATS + lane];
    float r = v * ar[hh * OUT_FEATS + lane];
    #pragma unroll
    for (int off = 32; off; off >>= 1) {
        l += __shfl_xor(l, off);
        r += __shfl_xor(r, off);
    }
    if (lane == 0) { el[gw] = l; er[gw] = r; }
}

// ---------------- CSR build ----------------
__global__ void hist_kernel(const int* __restrict__ dst, int* __restrict__ counts) {
    int e = blockIdx.x * blockDim.x + threadIdx.x;
    if (e < N_EDGES) atomicAdd(&counts[dst[e]], 1);
}

// single-block scan: 1024 threads x 10 elements each
__global__ __launch_bounds__(1024) void scan_fast(const int* __restrict__ counts,
                                                  int* __restrict__ row_ptr) {
    const int t = threadIdx.x;
    const int lane = t & 63, wid = t >> 6;
    int loc[10];
    int tot = 0;
    #pragma unroll
    for (int j = 0; j < 10; ++j) {
        int idx = t * 10 + j;
        int c = (idx < N_NODES) ? counts[idx] : 0;
        loc[j] = tot;
        tot += c;
    }
    int inc = tot;
    #pragma unroll
    for (int off = 1; off < 64; off <<= 1) {
        int nb = __shfl_up(inc, off);
        if (lane >= off) inc += nb;
    }
    __shared__ int wbase[16];
    if (lane == 63) wbase[wid] = inc;
    __syncthreads();
    if (t == 0) {
        int r = 0;
        #pragma unroll
        for (int i = 0; i < 16; ++i) { int x = wbase[i]; wbase[i] = r; r += x; }
    }
    __syncthreads();
    const int base = wbase[wid] + inc - tot;   // exclusive offset of this thread's chunk
    #pragma unroll
    for (int j = 0; j < 10; ++j) {
        int idx = t * 10 + j;
        if (idx < N_NODES) row_ptr[idx] = base + loc[j];
    }
    if (t == 1023) row_ptr[N_NODES] = base + tot;
}

__global__ void scatter_kernel(const int* __restrict__ src, const int* __restrict__ dst,
                               const int* __restrict__ row_ptr, int* __restrict__ cursor,
                               int* __restrict__ ssrc) {
    int e = blockIdx.x * blockDim.x + threadIdx.x;
    if (e >= N_EDGES) return;
    int d = dst[e];
    int pos = row_ptr[d] + atomicAdd(&cursor[d], 1);
    ssrc[pos] = src[e];
}

// ---------------- fused edge softmax -> alpha[hh][pos] ----------------
__global__ __launch_bounds__(256) void softmax_kernel(const float* __restrict__ el,
                                                      const float* __restrict__ er,
                                                      const int* __restrict__ row_ptr,
                                                      const int* __restrict__ ssrc,
                                                      float* __restrict__ alpha) {
    const int gw   = (blockIdx.x * blockDim.x + threadIdx.x) >> 6;
    const int lane = threadIdx.x & 63;
    if (gw >= N_NODES * HEADS) return;
    const int n  = gw >> 3;
    const int hh = gw & 7;
    const int beg = row_ptr[n];
    const int deg = row_ptr[n + 1] - beg;
    if (deg == 0) return;
    const float ern = er[gw];
    const int* sp = ssrc + beg;
    float* ap = alpha + (size_t)hh * N_EDGES + beg;

    if (deg <= 64) {
        float e = -INFINITY;
        if (lane < deg) {
            float x = el[sp[lane] * HEADS + hh] + ern;
            e = x > 0.f ? x : NEG_SLOPE * x;
        }
        float m = e;
        #pragma unroll
        for (int off = 32; off; off >>= 1) m = fmaxf(m, __shfl_xor(m, off));
        float p = (lane < deg) ? __expf(e - m) : 0.f;
        float s = p;
        #pragma unroll
        for (int off = 32; off; off >>= 1) s += __shfl_xor(s, off);
        const float inv = 1.0f / s;
        if (lane < deg) ap[lane] = p * inv;
    } else {
        float m = -INFINITY;
        for (int i = lane; i < deg; i += 64) {
            float x = el[sp[i] * HEADS + hh] + ern;
            x = x > 0.f ? x : NEG_SLOPE * x;
            m = fmaxf(m, x);
        }
        #pragma unroll
        for (int off = 32; off; off >>= 1) m = fmaxf(m, __shfl_xor(m, off));
        float s = 0.f;
        for (int i = lane; i < deg; i += 64) {
            float x = el[sp[i] * HEADS + hh] + ern;
            x = x > 0.f ? x : NEG_SLOPE * x;
            s += __expf(x - m);
        }
        #pragma unroll
        for (int off = 32; off; off >>= 1) s += __shfl_xor(s, off);
        const float inv = 1.0f / s;
        for (int i = lane; i < deg; i += 64) {
            float x = el[sp[i] * HEADS + hh] + ern;
            x = x > 0.f ? x : NEG_SLOPE * x;
            ap[i] = __expf(x - m) * inv;
        }
    }
}

// ---------------- aggregation: pure gather+fma, 4-way unrolled ----------------
__global__ __launch_bounds__(256) void aggregate_kernel(const float* __restrict__ h,
                                                        const float* __restrict__ alpha,
                                                        const float* __restrict__ bias,
                                                        const int* __restrict__ row_ptr,
                                                        const int* __restrict__ ssrc,
                                                        float* __restrict__ out) {
    const int gw   = (blockIdx.x * blockDim.x + threadIdx.x) >> 6;
    const int lane = threadIdx.x & 63;
    if (gw >= N_NODES * HEADS) return;
    const int n  = gw >> 3;
    const int hh = gw & 7;
    const int beg = row_ptr[n];
    const int deg = row_ptr[n + 1] - beg;
    const float bv = bias[hh * OUT_FEATS + lane];
    const size_t obase = (size_t)n * HF + hh * OUT_FEATS + lane;
    if (deg == 0) { out[obase] = bv; return; }

    const float* __restrict__ hb = h + hh * OUT_FEATS + lane;
    const float* __restrict__ ap = alpha + (size_t)hh * N_EDGES + beg;
    const int*   __restrict__ sp = ssrc + beg;

    float acc = 0.f;
    int k = 0;
    for (; k + 4 <= deg; k += 4) {
        int s0 = sp[k], s1 = sp[k + 1], s2 = sp[k + 2], s3 = sp[k + 3];
        float a0 = ap[k], a1 = ap[k + 1], a2 = ap[k + 2], a3 = ap[k + 3];
        float h0 = hb[(size_t)s0 * HF];
        float h1 = hb[(size_t)s1 * HF];
        float h2 = hb[(size_t)s2 * HF];
        float h3 = hb[(size_t)s3 * HF];
        acc = fmaf(a0, h0, acc);
        acc = fmaf(a1, h1, acc);
        acc = fmaf(a2, h2, acc);
        acc = fmaf(a3, h3, acc);
    }
    for (; k < deg; ++k)
        acc = fmaf(ap[k], hb[(size_t)sp[k] * HF], acc);
    out[obase] = acc + bv;
}

// ---------------- launch ----------------
extern "C" void kernel_launch(void* const* d_in, const int* in_sizes, int n_in,
                              void* d_out, int out_size, void* d_ws, size_t ws_size,
                              hipStream_t stream) {
    const float* feat   = (const float*)d_in[0];
    const float* W      = (const float*)d_in[1];
    const float* attn_l = (const float*)d_in[2];
    const float* attn_r = (const float*)d_in[3];
    const float* bias   = (const float*)d_in[4];
    const int*   src    = (const int*)d_in[5];
    const int*   dst    = (const int*)d_in[6];
    float* out = (float*)d_out;

    // workspace layout (8-byte-aligned chunks first)
    char* ws = (char*)d_ws;
    float*          h_buf  = (float*)ws;          ws += (size_t)N_NODES * HF * 4;       // 20.48 MB
    unsigned short* Bt_hi  = (unsigned short*)ws; ws += (size_t)IN_FEATS * HF * 2;      // 0.52 MB
    unsigned short* Bt_lo  = (unsigned short*)ws; ws += (size_t)IN_FEATS * HF * 2;      // 0.52 MB
    float*          alpha  = (float*)ws;          ws += (size_t)HEADS * N_EDGES * 4;    // 5.12 MB
    float*          el_buf = (float*)ws;          ws += (size_t)N_NODES * HEADS * 4;
    float*          er_buf = (float*)ws;          ws += (size_t)N_NODES * HEADS * 4;
    int*            row_ptr= (int*)ws;            ws += (size_t)(N_NODES + 1) * 4;
    int*            counts = (int*)ws;            ws += (size_t)N_NODES * 4;
    int*            cursor = (int*)ws;            ws += (size_t)N_NODES * 4;
    int*            ssrc   = (int*)ws;            ws += (size_t)N_EDGES * 4;

    zero_ints<<<(2 * N_NODES + 255) / 256, 256, 0, stream>>>(counts, 2 * N_NODES);

    dim3 wgrid(IN_FEATS / TW, HF / TW);
    prep_w<<<wgrid, 256, 0, stream>>>(W, Bt_hi, Bt_lo);

    dim3 ggrid((N_NODES + GTM - 1) / GTM, HF / GTN);
    gemm_mfma<<<ggrid, 256, 0, stream>>>(feat, Bt_hi, Bt_lo, h_buf, N_NODES);

    int nwaves = N_NODES * HEADS;
    eler_kernel<<<(nwaves * 64 + 255) / 256, 256, 0, stream>>>(h_buf, attn_l, attn_r, el_buf, er_buf);

    hist_kernel<<<(N_EDGES + 255) / 256, 256, 0, stream>>>(dst, counts);
    scan_fast<<<1, 1024, 0, stream>>>(counts, row_ptr);
    scatter_kernel<<<(N_EDGES + 255) / 256, 256, 0, stream>>>(src, dst, row_ptr, cursor, ssrc);

    softmax_kernel<<<(nwaves * 64 + 255) / 256, 256, 0, stream>>>(el_buf, er_buf, row_ptr, ssrc, alpha);

    aggregate_kernel<<<(nwaves * 64 + 255) / 256, 256, 0, stream>>>(
        h_buf, alpha, bias, row_ptr, ssrc, out);
}